// Round 2
// baseline (286.885 us; speedup 1.0000x reference)
//
#include <hip/hip_runtime.h>
#include <hip/hip_bf16.h>
#include <cstdint>

typedef unsigned short u16;
typedef __bf16 bf16x8 __attribute__((ext_vector_type(8)));
typedef float floatx4 __attribute__((ext_vector_type(4)));

#define AS1 __attribute__((address_space(1)))
#define AS3 __attribute__((address_space(3)))

// round-to-nearest-even f32 -> bf16 bits
static __device__ __forceinline__ u16 f2bf(float f) {
    union { float f; unsigned int u; } v; v.f = f;
    unsigned int u = v.u;
    return (u16)((u + 0x7FFFu + ((u >> 16) & 1u)) >> 16);
}

// raw barrier: no implicit vmcnt drain. sched_barrier(0) pins machine-sched
// motion; empty asm "memory" blocks IR-level motion of LDS/global ops.
static __device__ __forceinline__ void bar() {
    __builtin_amdgcn_sched_barrier(0);
    asm volatile("" ::: "memory");
    __builtin_amdgcn_s_barrier();
    asm volatile("" ::: "memory");
    __builtin_amdgcn_sched_barrier(0);
}

// ---------------------------------------------------------------------------
// Fused prep kernel (unchanged): blockIdx-partitioned into
//   [0, 4096)      : transpose+cvt w1 (1024x4096 -> W1t[4096][1024])
//   [4096, 8192)   : transpose+cvt w2 (4096x1024 -> W2t[1024][4096])
//   [8192, 16384)  : LayerNorm row (act row -> X row, bf16)
// ---------------------------------------------------------------------------
__device__ __forceinline__ void transpose_body(
    const float* __restrict__ in, u16* __restrict__ out,
    int R, int Ccols, int bx, int by, int tid, float (*tile)[33])
{
    const int tx = tid & 31;
    const int ty = tid >> 5;    // 0..7
    const int c0 = bx * 32;
    const int r0 = by * 32;
#pragma unroll
    for (int i = 0; i < 32; i += 8)
        tile[ty + i][tx] = in[(size_t)(r0 + ty + i) * Ccols + (c0 + tx)];
    __syncthreads();
#pragma unroll
    for (int i = 0; i < 32; i += 8)
        out[(size_t)(c0 + ty + i) * R + (r0 + tx)] = f2bf(tile[tx][ty + i]);
}

__global__ __launch_bounds__(256)
void prep(const float* __restrict__ w1, const float* __restrict__ w2,
          const float* __restrict__ act, const float* __restrict__ ln_scale,
          const float* __restrict__ ln_bias,
          u16* __restrict__ W1t, u16* __restrict__ W2t, u16* __restrict__ X)
{
    __shared__ float smem[32][33];   // transpose tile; LN uses first 8 floats
    const int id  = blockIdx.x;
    const int tid = threadIdx.x;

    if (id < 4096) {
        transpose_body(w1, W1t, 1024, 4096, id & 127, id >> 7, tid, smem);
        return;
    }
    if (id < 8192) {
        const int t = id - 4096;
        transpose_body(w2, W2t, 4096, 1024, t & 31, t >> 5, tid, smem);
        return;
    }
    // LayerNorm, one block per row
    const int row = id - 8192;
    const float4 v = ((const float4*)(act + (size_t)row * 1024))[tid];
    float s  = v.x + v.y + v.z + v.w;
    float ss = v.x * v.x + v.y * v.y + v.z * v.z + v.w * v.w;
#pragma unroll
    for (int off = 32; off > 0; off >>= 1) {
        s  += __shfl_xor(s, off, 64);
        ss += __shfl_xor(ss, off, 64);
    }
    float* red = &smem[0][0];
    const int wave = tid >> 6, lane = tid & 63;
    if (lane == 0) { red[wave] = s; red[4 + wave] = ss; }
    __syncthreads();
    s  = red[0] + red[1] + red[2] + red[3];
    ss = red[4] + red[5] + red[6] + red[7];
    const float mu  = s * (1.0f / 1024.0f);
    const float var = ss * (1.0f / 1024.0f) - mu * mu;
    const float rs  = rsqrtf(var + 1e-5f);
    const float4 sc = ((const float4*)ln_scale)[tid];
    const float4 bi = ((const float4*)ln_bias)[tid];
    ushort4 o;
    o.x = f2bf((v.x - mu) * rs * sc.x + bi.x);
    o.y = f2bf((v.y - mu) * rs * sc.y + bi.y);
    o.z = f2bf((v.z - mu) * rs * sc.z + bi.z);
    o.w = f2bf((v.w - mu) * rs * sc.w + bi.w);
    ((ushort4*)(X + (size_t)row * 1024))[tid] = o;
}

// ---------------------------------------------------------------------------
// R8: single-barrier-per-K-tile bf16 GEMM.
//
//   C[M][N] = A[M][K] * Bt[N][K]^T + bias (+ReLU)
//
// R7 post-mortem: both GEMMs ran at exactly ~1850 cy per phase (128 phases/CU
// -> 98.5us) vs ~620 cy of MFMA work: 2 raw barriers per phase locked all 8
// waves into the same phase, serializing the CU-wide LDS reads against MFMA
// with zero cross-phase overlap. Fix: ONE barrier + ONE vmcnt(0) per K-tile;
// no syncs inside the tile body, so compiler lgkmcnt scheduling + wave drift
// overlap ds_read with MFMA. B-frags are register-resident for the whole tile
// (8 x b128), A-frags streamed per mi (cuts LDS reads to the minimum
// (MF_M*2 + MF_N*2) b128 per wave per tile).
//
// Geometry: BM=256, BK=64, 512 thr = 8 waves.
//   BN=256: waves 2x4, wave tile 128x64, acc[8][4] (128 VGPR). grid GEMM1
//           = 32x16 = 512 (2 clean rounds at 1 block/CU, 128KB LDS).
//   BN=128: waves 4x2, wave tile 64x64, acc[4][4]. grid GEMM2 = 32x8 = 256
//           (exactly 1/CU, 96KB LDS).
//
// Pipeline: double buffer; during tile t stage tile t+1 into buf (t+1)&1
// (that buffer's readers finished at the barrier ending tile t-1 -> race
// free). Boundary: vmcnt(0) (all t+1 issues, made a full ~1000cy earlier)
// + raw barrier. Staging swizzle (proven 0-conflict R2..R7): row's 16B slot
// s stores global slot s ^ (row&7); frag read uses slot (kh*4+quad)^(l16&7).
// Requires: M%256==0, N%BN==0, K%64==0, K>=128.
// ---------------------------------------------------------------------------
template <int BN, bool BF16_OUT, bool RELU>
__global__ __launch_bounds__(512, 2)
void gemm_v8(const u16* __restrict__ A,      // [M][K] bf16 bits
             const u16* __restrict__ Bt,     // [N][K] bf16 bits
             const float* __restrict__ bias, // [N]
             void* __restrict__ Cout,
             int M, int N, int K)
{
    constexpr int BM   = 256, BK = 64;
    constexpr int WN   = BN / 64;            // waves along N (4 or 2)
    constexpr int WM   = 8 / WN;             // waves along M (2 or 4)
    constexpr int WTM  = BM / WM;            // wave rows: 128 or 64
    constexpr int MF_M = WTM / 16;           // 8 or 4
    constexpr int MF_N = 4;                  // wave cols fixed 64
    constexpr int ASZ  = BM * BK;            // u16 (32KB)
    constexpr int BSZ  = BN * BK;            // u16 (32KB or 16KB)
    constexpr int NCA  = BM / 64;            // A stage issues/wave = 4
    constexpr int NCB  = BN / 64;            // B stage issues/wave = 4 or 2

    __shared__ __align__(16) u16 Alds[2 * ASZ];
    __shared__ __align__(16) u16 Blds[2 * BSZ];

    const int tid  = threadIdx.x;
    const int wave = tid >> 6;
    const int lane = tid & 63;
    const int srow = lane >> 3;     // staging: row within 8-row chunk
    const int s_st = lane & 7;      // staging: stored 16B slot
    const int quad = lane >> 4;
    const int l16  = lane & 15;
    const int rkey = l16 & 7;       // read-side swizzle key (row&7)
    const int wm   = wave / WN;
    const int wn   = wave % WN;

    const int nbm = M >> 8;
    const int id  = blockIdx.x;
    const int bm  = id % nbm;       // bm-fastest (R5: swizzles hurt; keep)
    const int bn  = id / nbm;

    const u16* Ag = A  + (size_t)bm * BM * K;
    const u16* Bg = Bt + (size_t)bn * BN * K;

    // one stage issue = 8 waves x 64 lanes x 16B; per wave covers 8 rows.
    auto stageA = [&](int r, int k0, int ab) {
        const int ca  = wave * NCA + r;           // 0..31
        const int row = ca * 8 + srow;
        const int col = (s_st ^ (row & 7)) * 8;
        __builtin_amdgcn_global_load_lds(
            (AS1 void*)(Ag + (size_t)row * K + k0 + col),
            (AS3 void*)(&Alds[ab + ca * 512]), 16, 0, 0);
    };
    auto stageB = [&](int r, int k0, int bb) {
        const int cb  = wave * NCB + r;           // 0..BN/8-1
        const int row = cb * 8 + srow;
        const int col = (s_st ^ (row & 7)) * 8;
        __builtin_amdgcn_global_load_lds(
            (AS1 void*)(Bg + (size_t)row * K + k0 + col),
            (AS3 void*)(&Blds[bb + cb * 512]), 16, 0, 0);
    };

    floatx4 acc[MF_M][MF_N];
#pragma unroll
    for (int i = 0; i < MF_M; ++i)
#pragma unroll
        for (int j = 0; j < MF_N; ++j)
            acc[i][j] = (floatx4){0.f, 0.f, 0.f, 0.f};

    const int NT = K >> 6;

    // prologue: tile 0 -> buf 0; drain; sync.
#pragma unroll
    for (int r = 0; r < NCA; ++r) stageA(r, 0, 0);
#pragma unroll
    for (int r = 0; r < NCB; ++r) stageB(r, 0, 0);
    asm volatile("s_waitcnt vmcnt(0)" ::: "memory");
    bar();

    for (int t = 0; t < NT; ++t) {
        const int cur = t & 1;
        const int ab  = cur * ASZ;
        const int bb  = cur * BSZ;

        // issue next tile's staging first: full tile of latency to cover
        if (t + 1 < NT) {
            const int k1  = (t + 1) << 6;
            const int ab2 = (cur ^ 1) * ASZ;
            const int bb2 = (cur ^ 1) * BSZ;
#pragma unroll
            for (int r = 0; r < NCA; ++r) stageA(r, k1, ab2);
#pragma unroll
            for (int r = 0; r < NCB; ++r) stageB(r, k1, bb2);
        }

        // B-fragments register-resident for the whole tile
        bf16x8 bres[MF_N][2];
#pragma unroll
        for (int ni = 0; ni < MF_N; ++ni) {
            const int brow = wn * 64 + ni * 16 + l16;
#pragma unroll
            for (int kh = 0; kh < 2; ++kh) {
                const int slot = ((kh * 4 + quad) ^ rkey) * 8;
                bres[ni][kh] = *(const bf16x8*)&Blds[bb + brow * BK + slot];
            }
        }

#pragma unroll
        for (int mi = 0; mi < MF_M; ++mi) {
            const int arow = wm * WTM + mi * 16 + l16;
            const int sl0  = ((0 * 4 + quad) ^ rkey) * 8;
            const int sl1  = ((1 * 4 + quad) ^ rkey) * 8;
            const bf16x8 a0 = *(const bf16x8*)&Alds[ab + arow * BK + sl0];
            const bf16x8 a1 = *(const bf16x8*)&Alds[ab + arow * BK + sl1];
            __builtin_amdgcn_s_setprio(1);
#pragma unroll
            for (int ni = 0; ni < MF_N; ++ni)
                acc[mi][ni] = __builtin_amdgcn_mfma_f32_16x16x32_bf16(
                    bres[ni][0], a0, acc[mi][ni], 0, 0, 0);
#pragma unroll
            for (int ni = 0; ni < MF_N; ++ni)
                acc[mi][ni] = __builtin_amdgcn_mfma_f32_16x16x32_bf16(
                    bres[ni][1], a1, acc[mi][ni], 0, 0, 0);
            __builtin_amdgcn_s_setprio(0);
        }

        // boundary: next tile resident (issued a full tile ago) then sync
        if (t + 1 < NT)
            asm volatile("s_waitcnt vmcnt(0)" ::: "memory");
        bar();
    }

    // epilogue: lane (l16, quad) of acc[mi][ni] holds
    //   C[m = mbase+mi*16+l16][n = nbase+ni*16+quad*4 + r], r=0..3 contiguous
    const int mbase = bm * BM + wm * WTM;
    const int nbase = bn * BN + wn * 64;
#pragma unroll
    for (int mi = 0; mi < MF_M; ++mi) {
        const int m = mbase + mi * 16 + l16;
#pragma unroll
        for (int ni = 0; ni < MF_N; ++ni) {
            const int n0 = nbase + ni * 16 + quad * 4;
            const float4 bv = *(const float4*)&bias[n0];
            float v0 = acc[mi][ni][0] + bv.x;
            float v1 = acc[mi][ni][1] + bv.y;
            float v2 = acc[mi][ni][2] + bv.z;
            float v3 = acc[mi][ni][3] + bv.w;
            if (RELU) {
                v0 = fmaxf(v0, 0.f); v1 = fmaxf(v1, 0.f);
                v2 = fmaxf(v2, 0.f); v3 = fmaxf(v3, 0.f);
            }
            if (BF16_OUT) {
                ushort4 o = { f2bf(v0), f2bf(v1), f2bf(v2), f2bf(v3) };
                *(ushort4*)&((u16*)Cout)[(size_t)m * N + n0] = o;
            } else {
                float4 o = { v0, v1, v2, v3 };
                *(float4*)&((float*)Cout)[(size_t)m * N + n0] = o;
            }
        }
    }
}

// ---------------------------------------------------------------------------
// inputs: 0 act(4,2048,1024) f32, 1 mask(unused), 2 ln_scale(1024),
//         3 ln_bias(1024), 4 w1(1024,4096), 5 b1(4096), 6 w2(4096,1024),
//         7 b2(1024). out: (4,2048,1024) f32.
// ws layout (bf16 bits): X[8192*1024] | W1t[4096*1024] | W2t[1024*4096] |
//                        H[8192*4096]  -> 100,663,296 bytes total
// ---------------------------------------------------------------------------
extern "C" void kernel_launch(void* const* d_in, const int* in_sizes, int n_in,
                              void* d_out, int out_size, void* d_ws, size_t ws_size,
                              hipStream_t stream)
{
    const float* act      = (const float*)d_in[0];
    const float* ln_scale = (const float*)d_in[2];
    const float* ln_bias  = (const float*)d_in[3];
    const float* w1       = (const float*)d_in[4];
    const float* b1       = (const float*)d_in[5];
    const float* w2       = (const float*)d_in[6];
    const float* b2       = (const float*)d_in[7];
    float* out = (float*)d_out;

    const int M = 8192, C = 1024, CI = 4096;

    u16* X   = (u16*)d_ws;                 // [M][C]
    u16* W1t = X   + (size_t)M * C;        // [CI][C]
    u16* W2t = W1t + (size_t)CI * C;       // [C][CI]
    u16* H   = W2t + (size_t)C * CI;       // [M][CI]

    // fused prep: w1/w2 transpose+cvt + layernorm, one launch
    prep<<<16384, 256, 0, stream>>>(w1, w2, act, ln_scale, ln_bias, W1t, W2t, X);
    // H = relu(X @ W1 + b1), bf16. 256x256 tile: 512 blocks, 2 clean rounds.
    gemm_v8<256, true, true><<<(M / 256) * (CI / 256), 512, 0, stream>>>(
        X, W1t, b1, (void*)H, M, CI, C);
    // out = H @ W2 + b2, fp32. 256x128 tile: 256 blocks = exactly 1/CU.
    gemm_v8<128, false, false><<<(M / 256) * (C / 128), 512, 0, stream>>>(
        H, W2t, b2, (void*)out, M, C, CI);
}

// Round 4
// 268.185 us; speedup vs baseline: 1.0697x; 1.0697x over previous
//
#include <hip/hip_runtime.h>
#include <hip/hip_bf16.h>
#include <cstdint>

typedef unsigned short u16;
typedef __bf16 bf16x8 __attribute__((ext_vector_type(8)));
typedef float floatx4 __attribute__((ext_vector_type(4)));

#define AS1 __attribute__((address_space(1)))
#define AS3 __attribute__((address_space(3)))

#define SCHED0  __builtin_amdgcn_sched_barrier(0)
#define BARRIER __builtin_amdgcn_s_barrier()

// round-to-nearest-even f32 -> bf16 bits
static __device__ __forceinline__ u16 f2bf(float f) {
    union { float f; unsigned int u; } v; v.f = f;
    unsigned int u = v.u;
    return (u16)((u + 0x7FFFu + ((u >> 16) & 1u)) >> 16);
}

// ---------------------------------------------------------------------------
// Fused prep kernel (unchanged): blockIdx-partitioned into
//   [0, 4096)      : transpose+cvt w1 (1024x4096 -> W1t[4096][1024])
//   [4096, 8192)   : transpose+cvt w2 (4096x1024 -> W2t[1024][4096])
//   [8192, 16384)  : LayerNorm row (act row -> X row, bf16)
// ---------------------------------------------------------------------------
__device__ __forceinline__ void transpose_body(
    const float* __restrict__ in, u16* __restrict__ out,
    int R, int Ccols, int bx, int by, int tid, float (*tile)[33])
{
    const int tx = tid & 31;
    const int ty = tid >> 5;    // 0..7
    const int c0 = bx * 32;
    const int r0 = by * 32;
#pragma unroll
    for (int i = 0; i < 32; i += 8)
        tile[ty + i][tx] = in[(size_t)(r0 + ty + i) * Ccols + (c0 + tx)];
    __syncthreads();
#pragma unroll
    for (int i = 0; i < 32; i += 8)
        out[(size_t)(c0 + ty + i) * R + (r0 + tx)] = f2bf(tile[tx][ty + i]);
}

__global__ __launch_bounds__(256)
void prep(const float* __restrict__ w1, const float* __restrict__ w2,
          const float* __restrict__ act, const float* __restrict__ ln_scale,
          const float* __restrict__ ln_bias,
          u16* __restrict__ W1t, u16* __restrict__ W2t, u16* __restrict__ X)
{
    __shared__ float smem[32][33];   // transpose tile; LN uses first 8 floats
    const int id  = blockIdx.x;
    const int tid = threadIdx.x;

    if (id < 4096) {
        transpose_body(w1, W1t, 1024, 4096, id & 127, id >> 7, tid, smem);
        return;
    }
    if (id < 8192) {
        const int t = id - 4096;
        transpose_body(w2, W2t, 4096, 1024, t & 31, t >> 5, tid, smem);
        return;
    }
    // LayerNorm, one block per row
    const int row = id - 8192;
    const float4 v = ((const float4*)(act + (size_t)row * 1024))[tid];
    float s  = v.x + v.y + v.z + v.w;
    float ss = v.x * v.x + v.y * v.y + v.z * v.z + v.w * v.w;
#pragma unroll
    for (int off = 32; off > 0; off >>= 1) {
        s  += __shfl_xor(s, off, 64);
        ss += __shfl_xor(ss, off, 64);
    }
    float* red = &smem[0][0];
    const int wave = tid >> 6, lane = tid & 63;
    if (lane == 0) { red[wave] = s; red[4 + wave] = ss; }
    __syncthreads();
    s  = red[0] + red[1] + red[2] + red[3];
    ss = red[4] + red[5] + red[6] + red[7];
    const float mu  = s * (1.0f / 1024.0f);
    const float var = ss * (1.0f / 1024.0f) - mu * mu;
    const float rs  = rsqrtf(var + 1e-5f);
    const float4 sc = ((const float4*)ln_scale)[tid];
    const float4 bi = ((const float4*)ln_bias)[tid];
    ushort4 o;
    o.x = f2bf((v.x - mu) * rs * sc.x + bi.x);
    o.y = f2bf((v.y - mu) * rs * sc.y + bi.y);
    o.z = f2bf((v.z - mu) * rs * sc.z + bi.z);
    o.w = f2bf((v.w - mu) * rs * sc.w + bi.w);
    ((ushort4*)(X + (size_t)row * 1024))[tid] = o;
}

// ---------------------------------------------------------------------------
// R10 GEMM1 (= R9 resubmit, hardened): H = relu(X @ W1t^T + b1), bf16 out.
// M=8192 N=4096 K=1024.  m201-style phase schedule on BM=BN=256, BK=64,
// 8 waves (2M x 4N), wave tile 128x64, acc[8][4].
//
// Per K-tile: 4 phases. Phase p computes mi-pair {2p,2p+1} x 4 ni x 2 kh
// = 16 MFMA. Phase 0 additionally reads all B-frags (8 b128, register-
// resident for the tile); every phase reads 4 A b128. Each phase:
//   {ds_reads; stage 2 issues of t+1; BAR; lgkmcnt(0); sched0; setprio(1);
//    16 MFMA; setprio(0); [counted vmcnt]; BAR}
// Stage issues (1 issue = 64 rows = 8 waves x 8 rows x 128B) are
// consumption-ordered [A0,A2,B0,B1,B2,B3,A1,A3]: phase0/1 need the first 6
// (A rows 0-63,128-191 + all B); A1,A3 (rows 64-127,192-255) first needed
// at phase 2.  Waits:
//   end p1: vmcnt(4)  -> retires prev A1,A3 (oldest) before p2 reads them
//   end p3: vmcnt(2)  -> retires next tile's A0,A2,B0..B3; A1',A3' in flight
// Never vmcnt(0) mid-loop; loads live across barriers.
// Race-freedom: all phase ds_reads complete at that phase's lgkmcnt(0)
// (before MFMA); the p3-end barrier therefore orders ALL reads of buffer
// cb before any wave stages into it next tile. Barriers are uniform.
// LDS 128KB dbuf, 1 block/CU. Swizzle: stored slot = global ^ (row&7),
// read slot = (kh*4+quad) ^ (l16&7)  (proven 0-conflict R2..R8).
// ---------------------------------------------------------------------------
__global__ __launch_bounds__(512, 2)
void gemm1(const u16* __restrict__ A, const u16* __restrict__ Bt,
           const float* __restrict__ bias, u16* __restrict__ H)
{
    constexpr int K = 1024, N = 4096;
    constexpr int ASZ = 256 * 64;        // u16 per buffer (32KB)
    __shared__ __align__(16) u16 Alds[2 * ASZ];
    __shared__ __align__(16) u16 Blds[2 * ASZ];

    const int tid  = threadIdx.x;
    const int wave = tid >> 6;
    const int lane = tid & 63;
    const int srow = lane >> 3;
    const int sst  = lane & 7;
    const int quad = lane >> 4;
    const int l16  = lane & 15;
    const int rkey = l16 & 7;
    const int wm   = wave >> 2;          // 0..1
    const int wn   = wave & 3;           // 0..3

    const int id = blockIdx.x;
    const int bm = id & 31;              // nbm = 32, bm-fastest
    const int bn = id >> 5;              // 0..15

    const u16* Ag = A  + (size_t)bm * 256 * K;
    const u16* Bg = Bt + (size_t)bn * 256 * K;

    auto stA = [&](int buf, int c, int k0) {
        const int row = c * 64 + wave * 8 + srow;
        const int col = (sst ^ (row & 7)) * 8;
        __builtin_amdgcn_global_load_lds(
            (AS1 void*)(Ag + (size_t)row * K + k0 + col),
            (AS3 void*)(&Alds[buf * ASZ + c * 4096 + wave * 512]), 16, 0, 0);
    };
    auto stB = [&](int buf, int c, int k0) {
        const int row = c * 64 + wave * 8 + srow;
        const int col = (sst ^ (row & 7)) * 8;
        __builtin_amdgcn_global_load_lds(
            (AS1 void*)(Bg + (size_t)row * K + k0 + col),
            (AS3 void*)(&Blds[buf * ASZ + c * 4096 + wave * 512]), 16, 0, 0);
    };

    floatx4 acc[8][4];
#pragma unroll
    for (int i = 0; i < 8; ++i)
#pragma unroll
        for (int j = 0; j < 4; ++j)
            acc[i][j] = (floatx4){0.f, 0.f, 0.f, 0.f};

    constexpr int NT = K / 64;           // 16

    // prologue: tile0 -> buf0, consumption order
    stA(0, 0, 0); stA(0, 2, 0);
    stB(0, 0, 0); stB(0, 1, 0); stB(0, 2, 0); stB(0, 3, 0);
    stA(0, 1, 0); stA(0, 3, 0);
    asm volatile("s_waitcnt vmcnt(2)" ::: "memory");
    SCHED0; BARRIER; SCHED0;

    bf16x8 bres[4][2];
    for (int t = 0; t < NT; ++t) {
        const int cb = t & 1, nb = cb ^ 1;
        const int ab = cb * ASZ, bb = cb * ASZ;
        const int k1 = (t + 1) * 64;
        const bool st = (t + 1 < NT);

#pragma unroll
        for (int p = 0; p < 4; ++p) {
            if (p == 0) {
#pragma unroll
                for (int ni = 0; ni < 4; ++ni) {
                    const int br = wn * 64 + ni * 16 + l16;
#pragma unroll
                    for (int kh = 0; kh < 2; ++kh)
                        bres[ni][kh] = *(const bf16x8*)
                            &Blds[bb + br * 64 + ((kh * 4 + quad) ^ rkey) * 8];
                }
            }
            bf16x8 afr[2][2];
#pragma unroll
            for (int j = 0; j < 2; ++j) {
                const int ar = wm * 128 + (2 * p + j) * 16 + l16;
#pragma unroll
                for (int kh = 0; kh < 2; ++kh)
                    afr[j][kh] = *(const bf16x8*)
                        &Alds[ab + ar * 64 + ((kh * 4 + quad) ^ rkey) * 8];
            }
            if (st) {
                if (p == 0)      { stA(nb, 0, k1); stA(nb, 2, k1); }
                else if (p == 1) { stB(nb, 0, k1); stB(nb, 1, k1); }
                else if (p == 2) { stB(nb, 2, k1); stB(nb, 3, k1); }
                else             { stA(nb, 1, k1); stA(nb, 3, k1); }
            }
            SCHED0; BARRIER;
            asm volatile("s_waitcnt lgkmcnt(0)" ::: "memory");
            SCHED0;
            __builtin_amdgcn_s_setprio(1);
#pragma unroll
            for (int kh = 0; kh < 2; ++kh)
#pragma unroll
                for (int j = 0; j < 2; ++j)
#pragma unroll
                    for (int ni = 0; ni < 4; ++ni)
                        acc[2 * p + j][ni] = __builtin_amdgcn_mfma_f32_16x16x32_bf16(
                            bres[ni][kh], afr[j][kh], acc[2 * p + j][ni], 0, 0, 0);
            __builtin_amdgcn_s_setprio(0);
            SCHED0;
            if (p == 1) {
                if (st) asm volatile("s_waitcnt vmcnt(4)" ::: "memory");
                else    asm volatile("s_waitcnt vmcnt(0)" ::: "memory");
            }
            if (p == 3 && st)
                asm volatile("s_waitcnt vmcnt(2)" ::: "memory");
            BARRIER; SCHED0;
        }
    }

    // epilogue: bf16 + bias + relu
    const int mbase = bm * 256 + wm * 128;
    const int nbase = bn * 256 + wn * 64;
#pragma unroll
    for (int mi = 0; mi < 8; ++mi) {
        const int m = mbase + mi * 16 + l16;
#pragma unroll
        for (int ni = 0; ni < 4; ++ni) {
            const int n0 = nbase + ni * 16 + quad * 4;
            const float4 bv = *(const float4*)&bias[n0];
            float v0 = fmaxf(acc[mi][ni][0] + bv.x, 0.f);
            float v1 = fmaxf(acc[mi][ni][1] + bv.y, 0.f);
            float v2 = fmaxf(acc[mi][ni][2] + bv.z, 0.f);
            float v3 = fmaxf(acc[mi][ni][3] + bv.w, 0.f);
            ushort4 o = { f2bf(v0), f2bf(v1), f2bf(v2), f2bf(v3) };
            *(ushort4*)&H[(size_t)m * N + n0] = o;
        }
    }
}

// ---------------------------------------------------------------------------
// R10 GEMM2 (= R9 resubmit): out = H @ W2t^T + b2, fp32 out. M=8192 N=1024
// K=4096.  BM=256 BN=128 (grid 256 = exactly 1/CU), 8 waves (4M x 2N), wave
// tile 64x64, acc[4][4].  K-half-split LDS layout (A=[kh][256][32k],
// B=[kh][128][32k]) so each 8KB stage issue is one k-half. 2 phases/K-tile:
//   {8 ds_read (4A+4B); stage t+1's kh trio; BAR; lgkmcnt(0); setprio(1);
//    16 MFMA; setprio(0); vmcnt(3); BAR}
// Issue order [Ak0c0,Ak0c1,Bk0, Ak1c0,Ak1c1,Bk1] -> uniform vmcnt(3) at each
// phase end retires exactly the trio needed next (vmcnt(0) only entering the
// last tile's kh1).  Swizzle: 4 slots/row-half, key=(row>>1)&3 -> worst
// 2-way (free, m136).  LDS 96KB dbuf, 1 block/CU.
// ---------------------------------------------------------------------------
__global__ __launch_bounds__(512, 2)
void gemm2(const u16* __restrict__ A, const u16* __restrict__ Bt,
           const float* __restrict__ bias, float* __restrict__ Cout)
{
    constexpr int K = 4096, N = 1024;
    constexpr int ASZ = 2 * 256 * 32;    // u16 per buffer (32KB)
    constexpr int BSZ = 2 * 128 * 32;    // u16 per buffer (16KB)
    __shared__ __align__(16) u16 Alds[2 * ASZ];
    __shared__ __align__(16) u16 Blds[2 * BSZ];

    const int tid  = threadIdx.x;
    const int wave = tid >> 6;
    const int lane = tid & 63;
    const int quad = lane >> 4;
    const int l16  = lane & 15;
    const int key4 = (l16 >> 1) & 3;     // frag-read swizzle key
    const int wm   = wave >> 1;          // 0..3
    const int wn   = wave & 1;           // 0..1

    const int id = blockIdx.x;
    const int bm = id & 31;              // nbm = 32
    const int bn = id >> 5;              // 0..7

    const u16* Ag = A  + (size_t)bm * 256 * K;
    const u16* Bg = Bt + (size_t)bn * 128 * K;

    auto stA = [&](int buf, int kh, int c, int k0) {
        const int row = c * 128 + wave * 16 + (lane >> 2);
        const int col = kh * 32 + ((lane & 3) ^ ((row >> 1) & 3)) * 8;
        __builtin_amdgcn_global_load_lds(
            (AS1 void*)(Ag + (size_t)row * K + k0 + col),
            (AS3 void*)(&Alds[buf * ASZ + kh * 8192 + c * 4096 + wave * 512]),
            16, 0, 0);
    };
    auto stB = [&](int buf, int kh, int k0) {
        const int row = wave * 16 + (lane >> 2);
        const int col = kh * 32 + ((lane & 3) ^ ((row >> 1) & 3)) * 8;
        __builtin_amdgcn_global_load_lds(
            (AS1 void*)(Bg + (size_t)row * K + k0 + col),
            (AS3 void*)(&Blds[buf * BSZ + kh * 4096 + wave * 512]), 16, 0, 0);
    };

    floatx4 acc[4][4];
#pragma unroll
    for (int i = 0; i < 4; ++i)
#pragma unroll
        for (int j = 0; j < 4; ++j)
            acc[i][j] = (floatx4){0.f, 0.f, 0.f, 0.f};

    constexpr int NT = K / 64;           // 64

    // prologue: tile0 -> buf0, consumption order
    stA(0, 0, 0, 0); stA(0, 0, 1, 0); stB(0, 0, 0);
    stA(0, 1, 0, 0); stA(0, 1, 1, 0); stB(0, 1, 0);
    asm volatile("s_waitcnt vmcnt(3)" ::: "memory");
    SCHED0; BARRIER; SCHED0;

    for (int t = 0; t < NT; ++t) {
        const int cb = t & 1, nb = cb ^ 1;
        const int k1 = (t + 1) * 64;
        const bool st = (t + 1 < NT);

#pragma unroll
        for (int kh = 0; kh < 2; ++kh) {
            bf16x8 afr[4], bfr[4];
#pragma unroll
            for (int mi = 0; mi < 4; ++mi) {
                const int ar = wm * 64 + mi * 16 + l16;
                afr[mi] = *(const bf16x8*)
                    &Alds[cb * ASZ + kh * 8192 + ar * 32 + ((quad ^ key4) * 8)];
            }
#pragma unroll
            for (int ni = 0; ni < 4; ++ni) {
                const int br = wn * 64 + ni * 16 + l16;
                bfr[ni] = *(const bf16x8*)
                    &Blds[cb * BSZ + kh * 4096 + br * 32 + ((quad ^ key4) * 8)];
            }
            if (st) { stA(nb, kh, 0, k1); stA(nb, kh, 1, k1); stB(nb, kh, k1); }
            SCHED0; BARRIER;
            asm volatile("s_waitcnt lgkmcnt(0)" ::: "memory");
            SCHED0;
            __builtin_amdgcn_s_setprio(1);
#pragma unroll
            for (int mi = 0; mi < 4; ++mi)
#pragma unroll
                for (int ni = 0; ni < 4; ++ni)
                    acc[mi][ni] = __builtin_amdgcn_mfma_f32_16x16x32_bf16(
                        bfr[ni], afr[mi], acc[mi][ni], 0, 0, 0);
            __builtin_amdgcn_s_setprio(0);
            SCHED0;
            if (kh == 0) {
                if (st) asm volatile("s_waitcnt vmcnt(3)" ::: "memory");
                else    asm volatile("s_waitcnt vmcnt(0)" ::: "memory");
            } else if (st) {
                asm volatile("s_waitcnt vmcnt(3)" ::: "memory");
            }
            BARRIER; SCHED0;
        }
    }

    // epilogue: fp32 + bias
    const int mbase = bm * 256 + wm * 64;
    const int nbase = bn * 128 + wn * 64;
#pragma unroll
    for (int mi = 0; mi < 4; ++mi) {
        const int m = mbase + mi * 16 + l16;
#pragma unroll
        for (int ni = 0; ni < 4; ++ni) {
            const int n0 = nbase + ni * 16 + quad * 4;
            const float4 bv = *(const float4*)&bias[n0];
            float4 o = { acc[mi][ni][0] + bv.x, acc[mi][ni][1] + bv.y,
                         acc[mi][ni][2] + bv.z, acc[mi][ni][3] + bv.w };
            *(float4*)&Cout[(size_t)m * N + n0] = o;
        }
    }
}

// ---------------------------------------------------------------------------
// inputs: 0 act(4,2048,1024) f32, 1 mask(unused), 2 ln_scale(1024),
//         3 ln_bias(1024), 4 w1(1024,4096), 5 b1(4096), 6 w2(4096,1024),
//         7 b2(1024). out: (4,2048,1024) f32.
// ws layout (bf16 bits): X[8192*1024] | W1t[4096*1024] | W2t[1024*4096] |
//                        H[8192*4096]  -> 100,663,296 bytes total
// ---------------------------------------------------------------------------
extern "C" void kernel_launch(void* const* d_in, const int* in_sizes, int n_in,
                              void* d_out, int out_size, void* d_ws, size_t ws_size,
                              hipStream_t stream)
{
    const float* act      = (const float*)d_in[0];
    const float* ln_scale = (const float*)d_in[2];
    const float* ln_bias  = (const float*)d_in[3];
    const float* w1       = (const float*)d_in[4];
    const float* b1       = (const float*)d_in[5];
    const float* w2       = (const float*)d_in[6];
    const float* b2       = (const float*)d_in[7];
    float* out = (float*)d_out;

    const int M = 8192, C = 1024, CI = 4096;

    u16* X   = (u16*)d_ws;                 // [M][C]
    u16* W1t = X   + (size_t)M * C;        // [CI][C]
    u16* W2t = W1t + (size_t)CI * C;       // [C][CI]
    u16* H   = W2t + (size_t)C * CI;       // [M][CI]

    // fused prep: w1/w2 transpose+cvt + layernorm, one launch
    prep<<<16384, 256, 0, stream>>>(w1, w2, act, ln_scale, ln_bias, W1t, W2t, X);
    // H = relu(X @ W1 + b1): 512 blocks (2 rounds), 4-phase schedule
    gemm1<<<(M / 256) * (CI / 256), 512, 0, stream>>>(X, W1t, b1, H);
    // out = H @ W2 + b2: 256 blocks = exactly 1/CU, kh-split schedule
    gemm2<<<(M / 256) * (C / 128), 512, 0, stream>>>(H, W2t, b2, out);
}

// Round 5
// 248.970 us; speedup vs baseline: 1.1523x; 1.0772x over previous
//
#include <hip/hip_runtime.h>
#include <hip/hip_bf16.h>
#include <cstdint>

typedef unsigned short u16;
typedef __bf16 bf16x8 __attribute__((ext_vector_type(8)));
typedef float floatx4 __attribute__((ext_vector_type(4)));

#define AS1 __attribute__((address_space(1)))
#define AS3 __attribute__((address_space(3)))

#define SCHED0  __builtin_amdgcn_sched_barrier(0)
#define BARRIER __builtin_amdgcn_s_barrier()

// round-to-nearest-even f32 -> bf16 bits
static __device__ __forceinline__ u16 f2bf(float f) {
    union { float f; unsigned int u; } v; v.f = f;
    unsigned int u = v.u;
    return (u16)((u + 0x7FFFu + ((u >> 16) & 1u)) >> 16);
}

// LDS byte offset of a __shared__ address (AS3 pointers are 32-bit)
static __device__ __forceinline__ unsigned lds_off(const u16* p) {
    return (unsigned)(unsigned long long)(const AS3 u16*)p;
}
// inline-asm ds_read_b128: compiler does NOT see a memory op, so OUR manual
// lgkmcnt + sched_barrier(0) (rule #18) are the only ordering for consumers.
static __device__ __forceinline__ bf16x8 ds_read8(unsigned off) {
    bf16x8 r;
    asm volatile("ds_read_b128 %0, %1" : "=v"(r) : "v"(off));
    return r;
}

// ---------------------------------------------------------------------------
// R11 prep: transpose tiles are now 128 rows x 32 cols so each OUT row
// segment is 128 u16 = 256B, written by one wave as 64 x ushort2 (fully
// coalesced; old version wrote 64B segments). LN unchanged.
// blockIdx: [0,1024) w1-transpose, [1024,2048) w2-transpose, [2048,10240) LN.
// ---------------------------------------------------------------------------
__device__ __forceinline__ void transpose_body(
    const float* __restrict__ in, u16* __restrict__ out,
    int R, int Ccols, int bx, int by, int tid, float (*tile)[33])
{
    const int r0 = by * 128, c0 = bx * 32;
#pragma unroll
    for (int p = 0; p < 4; ++p) {
        const int f = p * 256 + tid;          // 0..1023 float4s
        const int r = f >> 3, c4 = (f & 7) * 4;
        const float4 v = *(const float4*)&in[(size_t)(r0 + r) * Ccols + c0 + c4];
        tile[r][c4 + 0] = v.x; tile[r][c4 + 1] = v.y;
        tile[r][c4 + 2] = v.z; tile[r][c4 + 3] = v.w;
    }
    __syncthreads();
    const int wv = tid >> 6, ln = tid & 63;
#pragma unroll
    for (int i = 0; i < 8; ++i) {
        const int c = i * 4 + wv;             // out-row (input col) 0..31
        ushort2 o = { f2bf(tile[ln * 2][c]), f2bf(tile[ln * 2 + 1][c]) };
        *(ushort2*)&out[(size_t)(c0 + c) * R + r0 + ln * 2] = o;
    }
}

__global__ __launch_bounds__(256)
void prep(const float* __restrict__ w1, const float* __restrict__ w2,
          const float* __restrict__ act, const float* __restrict__ ln_scale,
          const float* __restrict__ ln_bias,
          u16* __restrict__ W1t, u16* __restrict__ W2t, u16* __restrict__ X)
{
    __shared__ float tile[128][33];   // 16.9KB; LN reuses first 8 floats
    const int id  = blockIdx.x;
    const int tid = threadIdx.x;

    if (id < 1024) {          // w1 [1024][4096] -> W1t [4096][1024]
        transpose_body(w1, W1t, 1024, 4096, id & 127, id >> 7, tid, tile);
        return;
    }
    if (id < 2048) {          // w2 [4096][1024] -> W2t [1024][4096]
        const int t = id - 1024;
        transpose_body(w2, W2t, 4096, 1024, t & 31, t >> 5, tid, tile);
        return;
    }
    // LayerNorm, one block per row
    const int row = id - 2048;
    const float4 v = ((const float4*)(act + (size_t)row * 1024))[tid];
    float s  = v.x + v.y + v.z + v.w;
    float ss = v.x * v.x + v.y * v.y + v.z * v.z + v.w * v.w;
#pragma unroll
    for (int off = 32; off > 0; off >>= 1) {
        s  += __shfl_xor(s, off, 64);
        ss += __shfl_xor(ss, off, 64);
    }
    float* red = &tile[0][0];
    const int wave = tid >> 6, lane = tid & 63;
    if (lane == 0) { red[wave] = s; red[4 + wave] = ss; }
    __syncthreads();
    s  = red[0] + red[1] + red[2] + red[3];
    ss = red[4] + red[5] + red[6] + red[7];
    const float mu  = s * (1.0f / 1024.0f);
    const float var = ss * (1.0f / 1024.0f) - mu * mu;
    const float rs  = rsqrtf(var + 1e-5f);
    const float4 sc = ((const float4*)ln_scale)[tid];
    const float4 bi = ((const float4*)ln_bias)[tid];
    ushort4 o;
    o.x = f2bf((v.x - mu) * rs * sc.x + bi.x);
    o.y = f2bf((v.y - mu) * rs * sc.y + bi.y);
    o.z = f2bf((v.z - mu) * rs * sc.z + bi.z);
    o.w = f2bf((v.w - mu) * rs * sc.w + bi.w);
    ((ushort4*)(X + (size_t)row * 1024))[tid] = o;
}

// ---------------------------------------------------------------------------
// R11 GEMM1: H = relu(X @ W1t^T + b1), bf16.  M=8192 N=4096 K=1024.
// BM=BN=256, BK=64, 8 waves (2M x 4N), wave tile 128x64, acc[8][4].
// 4 phases/K-tile; CROSS-PHASE READ-AHEAD: phase p's MFMAs consume A-frags
// read in phase p-1 (p0 reads B(8)+Ap0(4)+Ap1(4); p1 reads Ap2; p2 reads
// Ap3; p3 reads none). All frag reads are inline-asm ds_read_b128 with
// manual counted lgkmcnt (p0:4, p1:4, p2:4, p3:0) + SCHED0 -> the MFMA
// cluster never waits on the current phase's LDS drain.
// ONE barrier per phase (the pre-MFMA barrier is gone: MFMA no longer
// depends on this phase's reads).
// Staging (dbuf, as R10): issue order per tile [A0,A2 | B0,B1 | B2,B3 |
// A1,A3]; phases 0-1 consume chunks {A0,A2}+B, phases 2-3 {A1,A3}.
// Wait ledger (oldest-first retirement):
//   end p0(t): outstanding [A1A3(t), A0A2(t+1)] -> st? vmcnt(2): vmcnt(0)
//              (retires A1A3(t) before p1's read-ahead of Ap2)
//   end p1/p2: no wait
//   end p3(t): outstanding [A0A2,B0B1,B2B3,A1A3](t+1) -> st? vmcnt(2)
//              (retires all p0(t+1) needs; A1A3(t+1) stays in flight)
// Swizzle (proven 0-conflict R2..R10): store slot = global ^ (row&7), read
// slot = (kh*4+quad) ^ (l16&7). LDS 128KB dbuf, 1 block/CU.
// ---------------------------------------------------------------------------
__global__ __launch_bounds__(512, 2)
void gemm1(const u16* __restrict__ A, const u16* __restrict__ Bt,
           const float* __restrict__ bias, u16* __restrict__ H)
{
    constexpr int K = 1024, N = 4096;
    constexpr int ASZ = 256 * 64;        // u16 per buffer (32KB)
    __shared__ __align__(16) u16 Alds[2 * ASZ];
    __shared__ __align__(16) u16 Blds[2 * ASZ];

    const int tid  = threadIdx.x;
    const int wave = tid >> 6;
    const int lane = tid & 63;
    const int srow = lane >> 3;
    const int sst  = lane & 7;
    const int quad = lane >> 4;
    const int l16  = lane & 15;
    const int rkey = l16 & 7;
    const int wm   = wave >> 2;          // 0..1
    const int wn   = wave & 3;           // 0..3

    const int id = blockIdx.x;
    const int bm = id & 31;
    const int bn = id >> 5;

    const u16* Ag = A  + (size_t)bm * 256 * K;
    const u16* Bg = Bt + (size_t)bn * 256 * K;

    auto stA = [&](int buf, int c, int k0) {
        const int row = c * 64 + wave * 8 + srow;
        const int col = (sst ^ (row & 7)) * 8;
        __builtin_amdgcn_global_load_lds(
            (AS1 void*)(Ag + (size_t)row * K + k0 + col),
            (AS3 void*)(&Alds[buf * ASZ + c * 4096 + wave * 512]), 16, 0, 0);
    };
    auto stB = [&](int buf, int c, int k0) {
        const int row = c * 64 + wave * 8 + srow;
        const int col = (sst ^ (row & 7)) * 8;
        __builtin_amdgcn_global_load_lds(
            (AS1 void*)(Bg + (size_t)row * K + k0 + col),
            (AS3 void*)(&Blds[buf * ASZ + c * 4096 + wave * 512]), 16, 0, 0);
    };

    // byte-offset bases for asm frag reads
    const unsigned Ab = lds_off(&Alds[0]);
    const unsigned Bb = lds_off(&Blds[0]);
    // per-lane constant parts: row*64 u16 + swizzled slot, in BYTES
    unsigned aoff[8][2], boff[4][2];
#pragma unroll
    for (int mi = 0; mi < 8; ++mi)
#pragma unroll
        for (int kh = 0; kh < 2; ++kh)
            aoff[mi][kh] = ((wm * 128 + mi * 16 + l16) * 64 +
                            ((kh * 4 + quad) ^ rkey) * 8) * 2;
#pragma unroll
    for (int ni = 0; ni < 4; ++ni)
#pragma unroll
        for (int kh = 0; kh < 2; ++kh)
            boff[ni][kh] = ((wn * 64 + ni * 16 + l16) * 64 +
                            ((kh * 4 + quad) ^ rkey) * 8) * 2;

    floatx4 acc[8][4];
#pragma unroll
    for (int i = 0; i < 8; ++i)
#pragma unroll
        for (int j = 0; j < 4; ++j)
            acc[i][j] = (floatx4){0.f, 0.f, 0.f, 0.f};

    constexpr int NT = K / 64;           // 16

    // prologue: tile0 -> buf0, consumption order; keep A1A3 in flight
    stA(0, 0, 0); stA(0, 2, 0);
    stB(0, 0, 0); stB(0, 1, 0); stB(0, 2, 0); stB(0, 3, 0);
    stA(0, 1, 0); stA(0, 3, 0);
    asm volatile("s_waitcnt vmcnt(2)" ::: "memory");
    SCHED0; BARRIER; SCHED0;

    bf16x8 bres[4][2];
    bf16x8 afr[2][2][2];                 // [slot][j][kh]
    for (int t = 0; t < NT; ++t) {
        const unsigned ab = Ab + (unsigned)((t & 1) * ASZ * 2);
        const unsigned bb = Bb + (unsigned)((t & 1) * ASZ * 2);
        const int nb = (t + 1) & 1;
        const int k1 = (t + 1) * 64;
        const bool st = (t + 1 < NT);

#pragma unroll
        for (int p = 0; p < 4; ++p) {
            // ---- reads (read-ahead by one phase) ----
            if (p == 0) {
#pragma unroll
                for (int ni = 0; ni < 4; ++ni)
#pragma unroll
                    for (int kh = 0; kh < 2; ++kh)
                        bres[ni][kh] = ds_read8(bb + boff[ni][kh]);
#pragma unroll
                for (int sl = 0; sl < 2; ++sl)      // Ap0 -> slot0, Ap1 -> slot1
#pragma unroll
                    for (int j = 0; j < 2; ++j)
#pragma unroll
                        for (int kh = 0; kh < 2; ++kh)
                            afr[sl][j][kh] = ds_read8(ab + aoff[sl * 2 + j][kh]);
            } else if (p < 3) {
#pragma unroll
                for (int j = 0; j < 2; ++j)         // A(p+1) -> slot (p+1)&1
#pragma unroll
                    for (int kh = 0; kh < 2; ++kh)
                        afr[(p + 1) & 1][j][kh] =
                            ds_read8(ab + aoff[(p + 1) * 2 + j][kh]);
            }
            // ---- stage next tile ----
            if (st) {
                if (p == 0)      { stA(nb, 0, k1); stA(nb, 2, k1); }
                else if (p == 1) { stB(nb, 0, k1); stB(nb, 1, k1); }
                else if (p == 2) { stB(nb, 2, k1); stB(nb, 3, k1); }
                else             { stA(nb, 1, k1); stA(nb, 3, k1); }
            }
            // ---- counted lgkm wait for the frags THIS phase consumes ----
            if (p == 3) asm volatile("s_waitcnt lgkmcnt(0)" ::: "memory");
            else        asm volatile("s_waitcnt lgkmcnt(4)" ::: "memory");
            SCHED0;
            __builtin_amdgcn_s_setprio(1);
#pragma unroll
            for (int kh = 0; kh < 2; ++kh)
#pragma unroll
                for (int j = 0; j < 2; ++j)
#pragma unroll
                    for (int ni = 0; ni < 4; ++ni)
                        acc[2 * p + j][ni] = __builtin_amdgcn_mfma_f32_16x16x32_bf16(
                            bres[ni][kh], afr[p & 1][j][kh], acc[2 * p + j][ni], 0, 0, 0);
            __builtin_amdgcn_s_setprio(0);
            SCHED0;
            // ---- counted vmcnt (ledger in header comment) ----
            if (p == 0) {
                if (st) asm volatile("s_waitcnt vmcnt(2)" ::: "memory");
                else    asm volatile("s_waitcnt vmcnt(0)" ::: "memory");
            }
            if (p == 3 && st)
                asm volatile("s_waitcnt vmcnt(2)" ::: "memory");
            BARRIER; SCHED0;
        }
    }

    // epilogue: bf16 + bias + relu
    const int mbase = bm * 256 + wm * 128;
    const int nbase = bn * 256 + wn * 64;
#pragma unroll
    for (int mi = 0; mi < 8; ++mi) {
        const int m = mbase + mi * 16 + l16;
#pragma unroll
        for (int ni = 0; ni < 4; ++ni) {
            const int n0 = nbase + ni * 16 + quad * 4;
            const float4 bv = *(const float4*)&bias[n0];
            float v0 = fmaxf(acc[mi][ni][0] + bv.x, 0.f);
            float v1 = fmaxf(acc[mi][ni][1] + bv.y, 0.f);
            float v2 = fmaxf(acc[mi][ni][2] + bv.z, 0.f);
            float v3 = fmaxf(acc[mi][ni][3] + bv.w, 0.f);
            ushort4 o = { f2bf(v0), f2bf(v1), f2bf(v2), f2bf(v3) };
            *(ushort4*)&H[(size_t)m * N + n0] = o;
        }
    }
}

// ---------------------------------------------------------------------------
// R11 GEMM2: out = H @ W2t^T + b2, fp32.  M=8192 N=1024 K=4096.
// BM=256 BN=128 (grid 256 = 1/CU), 8 waves (4M x 2N), wave tile 64x64.
// TRIPLE-buffered kh-split LDS (3 x 48KB = 144KB) enables CROSS-TILE frag
// read-ahead: phase kh consumes frags read last phase; kh0(t) reads
// (t,kh1) from buf t%3, kh1(t) reads (t+1,kh0) from buf (t+1)%3. Staging
// runs 2 tiles ahead (trio(t+2,kh) issued in phase kh of t).
// Wait ledger (oldest-first; trio = 3 issues):
//   end kh0(t): out [t+1k1, t+2k0] (+t+1k0 retired by this wait):
//               t+2<NT? vmcnt(6) : t+1<NT? vmcnt(3) : none
//   end kh1(t): out [t+1k1, t+2k0, t+2k1] -> retire t+1k1:
//               t+2<NT? vmcnt(6) : t+1<NT? vmcnt(0) : none
// lgkm: 8 asm ds_reads per phase -> lgkmcnt(8) (0 on last phase, which
// issues no reads). One barrier per phase. Stage writes go to buf (t+2)%3
// = (t-1)%3 whose last reads (kh0(t-1)) are >= 2 barriers old -> race-free.
// ---------------------------------------------------------------------------
__global__ __launch_bounds__(512, 2)
void gemm2(const u16* __restrict__ A, const u16* __restrict__ Bt,
           const float* __restrict__ bias, float* __restrict__ Cout)
{
    constexpr int K = 4096, N = 1024;
    constexpr int ASZ = 2 * 256 * 32;    // u16 per buffer (32KB)
    constexpr int BSZ = 2 * 128 * 32;    // u16 per buffer (16KB)
    __shared__ __align__(16) u16 Alds[3 * ASZ];   // 96KB
    __shared__ __align__(16) u16 Blds[3 * BSZ];   // 48KB

    const int tid  = threadIdx.x;
    const int wave = tid >> 6;
    const int lane = tid & 63;
    const int quad = lane >> 4;
    const int l16  = lane & 15;
    const int key4 = (l16 >> 1) & 3;
    const int wm   = wave >> 1;          // 0..3
    const int wn   = wave & 1;           // 0..1

    const int id = blockIdx.x;
    const int bm = id & 31;
    const int bn = id >> 5;

    const u16* Ag = A  + (size_t)bm * 256 * K;
    const u16* Bg = Bt + (size_t)bn * 128 * K;

    auto stA = [&](int buf, int kh, int c, int k0) {
        const int row = c * 128 + wave * 16 + (lane >> 2);
        const int col = kh * 32 + ((lane & 3) ^ ((row >> 1) & 3)) * 8;
        __builtin_amdgcn_global_load_lds(
            (AS1 void*)(Ag + (size_t)row * K + k0 + col),
            (AS3 void*)(&Alds[buf * ASZ + kh * 8192 + c * 4096 + wave * 512]),
            16, 0, 0);
    };
    auto stB = [&](int buf, int kh, int k0) {
        const int row = wave * 16 + (lane >> 2);
        const int col = kh * 32 + ((lane & 3) ^ ((row >> 1) & 3)) * 8;
        __builtin_amdgcn_global_load_lds(
            (AS1 void*)(Bg + (size_t)row * K + k0 + col),
            (AS3 void*)(&Blds[buf * BSZ + kh * 4096 + wave * 512]), 16, 0, 0);
    };

    const unsigned Ab = lds_off(&Alds[0]);
    const unsigned Bb = lds_off(&Blds[0]);
    unsigned aoff[4], boff[4];           // per-lane, excl. buf & kh
#pragma unroll
    for (int mi = 0; mi < 4; ++mi)
        aoff[mi] = ((wm * 64 + mi * 16 + l16) * 32 + (quad ^ key4) * 8) * 2;
#pragma unroll
    for (int ni = 0; ni < 4; ++ni)
        boff[ni] = ((wn * 64 + ni * 16 + l16) * 32 + (quad ^ key4) * 8) * 2;

    floatx4 acc[4][4];
#pragma unroll
    for (int i = 0; i < 4; ++i)
#pragma unroll
        for (int j = 0; j < 4; ++j)
            acc[i][j] = (floatx4){0.f, 0.f, 0.f, 0.f};

    constexpr int NT = K / 64;           // 64

    // prologue: stage t0 (buf0) + t1 (buf1); retire t0 fully
    stA(0, 0, 0, 0);  stA(0, 0, 1, 0);  stB(0, 0, 0);
    stA(0, 1, 0, 0);  stA(0, 1, 1, 0);  stB(0, 1, 0);
    stA(1, 0, 0, 64); stA(1, 0, 1, 64); stB(1, 0, 64);
    stA(1, 1, 0, 64); stA(1, 1, 1, 64); stB(1, 1, 64);
    asm volatile("s_waitcnt vmcnt(6)" ::: "memory");
    SCHED0; BARRIER; SCHED0;

    bf16x8 fa[2][4], fb[2][4];
    // preload (t0, kh0) from buf0
#pragma unroll
    for (int i = 0; i < 4; ++i) {
        fa[0][i] = ds_read8(Ab + aoff[i]);
        fb[0][i] = ds_read8(Bb + boff[i]);
    }

    int bs0 = 0, bs1 = 1, bs2 = 2;       // buffers of t, t+1, t+2
    for (int t = 0; t < NT; ++t) {
        const int k2 = (t + 2) * 64;
        const bool st  = (t + 2 < NT);
        const bool rd1 = (t + 1 < NT);
        const unsigned a0 = Ab + (unsigned)(bs0 * ASZ * 2);
        const unsigned b0 = Bb + (unsigned)(bs0 * BSZ * 2);
        const unsigned a1 = Ab + (unsigned)(bs1 * ASZ * 2);
        const unsigned b1 = Bb + (unsigned)(bs1 * BSZ * 2);

        // ---------------- phase kh=0: MFMA on fa/fb[0]; read (t,kh1) ------
#pragma unroll
        for (int i = 0; i < 4; ++i) {
            fa[1][i] = ds_read8(a0 + 16384u + aoff[i]);   // kh1: +8192 u16
            fb[1][i] = ds_read8(b0 + 8192u  + boff[i]);   // kh1: +4096 u16
        }
        if (st) { stA(bs2, 0, 0, k2); stA(bs2, 0, 1, k2); stB(bs2, 0, k2); }
        asm volatile("s_waitcnt lgkmcnt(8)" ::: "memory");
        SCHED0;
        __builtin_amdgcn_s_setprio(1);
#pragma unroll
        for (int mi = 0; mi < 4; ++mi)
#pragma unroll
            for (int ni = 0; ni < 4; ++ni)
                acc[mi][ni] = __builtin_amdgcn_mfma_f32_16x16x32_bf16(
                    fb[0][ni], fa[0][mi], acc[mi][ni], 0, 0, 0);
        __builtin_amdgcn_s_setprio(0);
        SCHED0;
        if (st)       asm volatile("s_waitcnt vmcnt(6)" ::: "memory");
        else if (rd1) asm volatile("s_waitcnt vmcnt(3)" ::: "memory");
        BARRIER; SCHED0;

        // ---------------- phase kh=1: MFMA on fa/fb[1]; read (t+1,kh0) ----
        if (rd1) {
#pragma unroll
            for (int i = 0; i < 4; ++i) {
                fa[0][i] = ds_read8(a1 + aoff[i]);
                fb[0][i] = ds_read8(b1 + boff[i]);
            }
        }
        if (st) { stA(bs2, 1, 0, k2); stA(bs2, 1, 1, k2); stB(bs2, 1, k2); }
        if (rd1) asm volatile("s_waitcnt lgkmcnt(8)" ::: "memory");
        else     asm volatile("s_waitcnt lgkmcnt(0)" ::: "memory");
        SCHED0;
        __builtin_amdgcn_s_setprio(1);
#pragma unroll
        for (int mi = 0; mi < 4; ++mi)
#pragma unroll
            for (int ni = 0; ni < 4; ++ni)
                acc[mi][ni] = __builtin_amdgcn_mfma_f32_16x16x32_bf16(
                    fb[1][ni], fa[1][mi], acc[mi][ni], 0, 0, 0);
        __builtin_amdgcn_s_setprio(0);
        SCHED0;
        if (st)       asm volatile("s_waitcnt vmcnt(6)" ::: "memory");
        else if (rd1) asm volatile("s_waitcnt vmcnt(0)" ::: "memory");
        BARRIER; SCHED0;

        const int tmp = bs0; bs0 = bs1; bs1 = bs2; bs2 = tmp;
    }

    // epilogue: fp32 + bias
    const int mbase = bm * 256 + wm * 64;
    const int nbase = bn * 128 + wn * 64;
#pragma unroll
    for (int mi = 0; mi < 4; ++mi) {
        const int m = mbase + mi * 16 + l16;
#pragma unroll
        for (int ni = 0; ni < 4; ++ni) {
            const int n0 = nbase + ni * 16 + quad * 4;
            const float4 bv = *(const float4*)&bias[n0];
            float4 o = { acc[mi][ni][0] + bv.x, acc[mi][ni][1] + bv.y,
                         acc[mi][ni][2] + bv.z, acc[mi][ni][3] + bv.w };
            *(float4*)&Cout[(size_t)m * N + n0] = o;
        }
    }
}

// ---------------------------------------------------------------------------
// inputs: 0 act(4,2048,1024) f32, 1 mask(unused), 2 ln_scale(1024),
//         3 ln_bias(1024), 4 w1(1024,4096), 5 b1(4096), 6 w2(4096,1024),
//         7 b2(1024). out: (4,2048,1024) f32.
// ws layout (bf16 bits): X[8192*1024] | W1t[4096*1024] | W2t[1024*4096] |
//                        H[8192*4096]  -> 100,663,296 bytes total
// ---------------------------------------------------------------------------
extern "C" void kernel_launch(void* const* d_in, const int* in_sizes, int n_in,
                              void* d_out, int out_size, void* d_ws, size_t ws_size,
                              hipStream_t stream)
{
    const float* act      = (const float*)d_in[0];
    const float* ln_scale = (const float*)d_in[2];
    const float* ln_bias  = (const float*)d_in[3];
    const float* w1       = (const float*)d_in[4];
    const float* b1       = (const float*)d_in[5];
    const float* w2       = (const float*)d_in[6];
    const float* b2       = (const float*)d_in[7];
    float* out = (float*)d_out;

    const int M = 8192, C = 1024, CI = 4096;

    u16* X   = (u16*)d_ws;                 // [M][C]
    u16* W1t = X   + (size_t)M * C;        // [CI][C]
    u16* W2t = W1t + (size_t)CI * C;       // [C][CI]
    u16* H   = W2t + (size_t)C * CI;       // [M][CI]

    // fused prep: w1/w2 transpose+cvt (256B out segments) + layernorm
    prep<<<10240, 256, 0, stream>>>(w1, w2, act, ln_scale, ln_bias, W1t, W2t, X);
    // H = relu(X @ W1 + b1): 512 blocks, read-ahead 4-phase schedule
    gemm1<<<(M / 256) * (CI / 256), 512, 0, stream>>>(X, W1t, b1, H);
    // out = H @ W2 + b2: 256 blocks, cross-tile read-ahead, 3-buffer LDS
    gemm2<<<(M / 256) * (C / 128), 512, 0, stream>>>(H, W2t, b2, out);
}